// Round 1
// baseline (801.091 us; speedup 1.0000x reference)
//
#include <hip/hip_runtime.h>
#include <math.h>

#define B_ 128
#define S_ 1024
#define D_ 256          // D == A == O == 256
#define PAD 260         // row pitch in LDS floats (multiple of 4 -> 16B-aligned float4)

__device__ __forceinline__ float wred_add(float x) {
#pragma unroll
    for (int off = 32; off > 0; off >>= 1) x += __shfl_xor(x, off, 64);
    return x;
}
__device__ __forceinline__ float wred_max(float x) {
#pragma unroll
    for (int off = 32; off > 0; off >>= 1) x = fmaxf(x, __shfl_xor(x, off, 64));
    return x;
}

// One block = 16 consecutive rows (b,s). 4 waves; wave w owns rows 4w..4w+3 (all 256 cols).
__global__ __launch_bounds__(256) void k_rows(
    const float* __restrict__ x, const float* __restrict__ mask,
    const float* __restrict__ W, const float* __restrict__ bo,
    const float* __restrict__ u, const float* __restrict__ Uo,
    float* __restrict__ vu_out,   // [B*S] masked vu (parked in alphas region)
    float* __restrict__ betas)    // [B*S, 256]
{
    __shared__ float xs[16 * PAD];
    __shared__ float vs[16 * PAD];
    const int tid  = threadIdx.x;
    const int lane = tid & 63;
    const int wid  = tid >> 6;
    const int row0 = blockIdx.x * 16;   // global row base
    const int c0   = lane * 4;          // this thread's 4 output columns
    const int r0   = wid * 4;           // this wave's 4 local rows

    // ---- stage x tile [16][256] row-major (writes: lane-stride 1 word -> conflict-free)
#pragma unroll
    for (int k = 0; k < 16; ++k)
        xs[k * PAD + tid] = x[(size_t)(row0 + k) * D_ + tid];
    __syncthreads();

    // ---- GEMM1: t[16][256] = x @ W  (4x4 register tile / thread)
    float acc[4][4];
#pragma unroll
    for (int i = 0; i < 4; ++i)
#pragma unroll
        for (int j = 0; j < 4; ++j) acc[i][j] = 0.f;

    for (int d4 = 0; d4 < 64; ++d4) {
        float xv[4][4];
#pragma unroll
        for (int i = 0; i < 4; ++i) {
            const float4 t = *(const float4*)&xs[(r0 + i) * PAD + 4 * d4]; // wave-uniform -> broadcast
            xv[i][0] = t.x; xv[i][1] = t.y; xv[i][2] = t.z; xv[i][3] = t.w;
        }
#pragma unroll
        for (int k = 0; k < 4; ++k) {
            const float4 wv = *(const float4*)&W[(size_t)(4 * d4 + k) * D_ + c0]; // coalesced
#pragma unroll
            for (int i = 0; i < 4; ++i) {
                acc[i][0] += xv[i][k] * wv.x;
                acc[i][1] += xv[i][k] * wv.y;
                acc[i][2] += xv[i][k] * wv.z;
                acc[i][3] += xv[i][k] * wv.w;
            }
        }
        if ((d4 & 15) == 15) __syncthreads();   // keep waves in lockstep for L1 reuse of W
    }

    // ---- bias
    {
        const float4 b4 = *(const float4*)&bo[c0];
#pragma unroll
        for (int i = 0; i < 4; ++i) {
            acc[i][0] += b4.x; acc[i][1] += b4.y; acc[i][2] += b4.z; acc[i][3] += b4.w;
        }
    }

    // ---- row L2 norm (wave owns whole row) + tanh
    float inv[4];
#pragma unroll
    for (int i = 0; i < 4; ++i) {
        float ss = acc[i][0]*acc[i][0] + acc[i][1]*acc[i][1]
                 + acc[i][2]*acc[i][2] + acc[i][3]*acc[i][3];
        ss = wred_add(ss);
        inv[i] = 1.f / fmaxf(sqrtf(ss), 1e-12f);
    }

    float m[4];
#pragma unroll
    for (int i = 0; i < 4; ++i) m[i] = mask[row0 + r0 + i];

    const float4 u4 = *(const float4*)&u[c0];
    float v[4][4];
#pragma unroll
    for (int i = 0; i < 4; ++i) {
#pragma unroll
        for (int j = 0; j < 4; ++j) v[i][j] = tanhf(acc[i][j] * inv[i]);
        float vup = v[i][0]*u4.x + v[i][1]*u4.y + v[i][2]*u4.z + v[i][3]*u4.w;
        vup = wred_add(vup);
        if (lane == 0) vu_out[row0 + r0 + i] = vup * m[i];
    }

    // ---- v -> LDS (contiguous float4 per row -> conflict-free)
#pragma unroll
    for (int i = 0; i < 4; ++i)
        *(float4*)&vs[(r0 + i) * PAD + c0] = make_float4(v[i][0], v[i][1], v[i][2], v[i][3]);
    __syncthreads();

    // ---- GEMM2: vuo[16][256] = v @ Uo
    float vo[4][4];
#pragma unroll
    for (int i = 0; i < 4; ++i)
#pragma unroll
        for (int j = 0; j < 4; ++j) vo[i][j] = 0.f;

    for (int a4 = 0; a4 < 64; ++a4) {
        float vv[4][4];
#pragma unroll
        for (int i = 0; i < 4; ++i) {
            const float4 t = *(const float4*)&vs[(r0 + i) * PAD + 4 * a4];
            vv[i][0] = t.x; vv[i][1] = t.y; vv[i][2] = t.z; vv[i][3] = t.w;
        }
#pragma unroll
        for (int k = 0; k < 4; ++k) {
            const float4 uo = *(const float4*)&Uo[(size_t)(4 * a4 + k) * D_ + c0];
#pragma unroll
            for (int i = 0; i < 4; ++i) {
                vo[i][0] += vv[i][k] * uo.x;
                vo[i][1] += vv[i][k] * uo.y;
                vo[i][2] += vv[i][k] * uo.z;
                vo[i][3] += vv[i][k] * uo.w;
            }
        }
        if ((a4 & 15) == 15) __syncthreads();
    }

    // ---- betas: masked softmax over the 256 cols of each row
#pragma unroll
    for (int i = 0; i < 4; ++i) {
#pragma unroll
        for (int j = 0; j < 4; ++j) vo[i][j] *= m[i];
        float mx = fmaxf(fmaxf(vo[i][0], vo[i][1]), fmaxf(vo[i][2], vo[i][3]));
        mx = wred_max(mx);
        float p[4]; float s = 0.f;
#pragma unroll
        for (int j = 0; j < 4; ++j) { p[j] = expf(vo[i][j] - mx) * m[i]; s += p[j]; }
        s = wred_add(s);
        const float r = 1.f / ((s == 0.f) ? 1.f : s);
        *(float4*)&betas[(size_t)(row0 + r0 + i) * D_ + c0] =
            make_float4(p[0]*r, p[1]*r, p[2]*r, p[3]*r);
    }
}

// One block per batch b: masked softmax over S (in-place on the vu/alphas region).
__global__ __launch_bounds__(256) void k_alphas(
    const float* __restrict__ mask, float* __restrict__ a)
{
    const int b = blockIdx.x;
    const int tid = threadIdx.x, lane = tid & 63, wid = tid >> 6;
    __shared__ float red[4];
    const int base = b * S_;
    float vals[4], mk[4];
#pragma unroll
    for (int k = 0; k < 4; ++k) {
        vals[k] = a[base + tid + 256 * k];     // already masked vu
        mk[k]   = mask[base + tid + 256 * k];
    }
    float mx = fmaxf(fmaxf(vals[0], vals[1]), fmaxf(vals[2], vals[3]));
    mx = wred_max(mx);
    if (lane == 0) red[wid] = mx;
    __syncthreads();
    mx = fmaxf(fmaxf(red[0], red[1]), fmaxf(red[2], red[3]));
    __syncthreads();
    float e[4], s = 0.f;
#pragma unroll
    for (int k = 0; k < 4; ++k) { e[k] = expf(vals[k] - mx) * mk[k]; s += e[k]; }
    s = wred_add(s);
    if (lane == 0) red[wid] = s;
    __syncthreads();
    s = red[0] + red[1] + red[2] + red[3];
    const float r = 1.f / ((s == 0.f) ? 1.f : s);
#pragma unroll
    for (int k = 0; k < 4; ++k) a[base + tid + 256 * k] = e[k] * r;
}

// out[b,d] = sum_s alphas[b,s] * betas[b,s,d] * x[b,s,d]; 8 blocks per batch, atomic combine.
__global__ __launch_bounds__(256) void k_out(
    const float* __restrict__ x, const float* __restrict__ alphas,
    const float* __restrict__ betas, float* __restrict__ out)
{
    const int bx = blockIdx.x;
    const int b = bx >> 3, chunk = bx & 7;
    const int tid = threadIdx.x;
    float acc = 0.f;
    const int sbeg = chunk * 128;
    for (int si = 0; si < 128; ++si) {
        const int s = sbeg + si;
        const float al = alphas[b * S_ + s];   // wave-uniform scalar load
        if (al != 0.f) {                        // masked rows contribute 0 (alphas==0)
            const size_t off = (size_t)(b * S_ + s) * D_ + tid;
            acc += al * betas[off] * x[off];
        }
    }
    atomicAdd(&out[b * D_ + tid], acc);
}

extern "C" void kernel_launch(void* const* d_in, const int* in_sizes, int n_in,
                              void* d_out, int out_size, void* d_ws, size_t ws_size,
                              hipStream_t stream) {
    const float* x    = (const float*)d_in[0];
    const float* mask = (const float*)d_in[1];
    const float* W    = (const float*)d_in[2];
    const float* bo   = (const float*)d_in[3];
    const float* u    = (const float*)d_in[4];
    const float* Uo   = (const float*)d_in[5];

    float* out    = (float*)d_out;             // [B, 256]
    float* alphas = out + B_ * D_;             // [B, S]
    float* betas  = alphas + (size_t)B_ * S_;  // [B, S, 256]

    hipMemsetAsync(out, 0, (size_t)B_ * D_ * sizeof(float), stream);
    k_rows  <<<B_ * S_ / 16, 256, 0, stream>>>(x, mask, W, bo, u, Uo, alphas, betas);
    k_alphas<<<B_,           256, 0, stream>>>(mask, alphas);
    k_out   <<<B_ * 8,       256, 0, stream>>>(x, alphas, betas, out);
}

// Round 2
// 382.323 us; speedup vs baseline: 2.0953x; 2.0953x over previous
//
#include <hip/hip_runtime.h>
#include <math.h>

#define B_ 128
#define S_ 1024
#define D_ 256          // D == A == O == 256
#define XP 264          // LDS bf16 row pitch (528 B: 4-bank row shift, 16B-aligned)

using bf16x8 = __attribute__((ext_vector_type(8))) __bf16;
using bf16x4 = __attribute__((ext_vector_type(4))) __bf16;
using f32x4  = __attribute__((ext_vector_type(4))) float;

__device__ __forceinline__ float qred_add(float v) {   // reduce across 16-lane group
    v += __shfl_xor(v, 1); v += __shfl_xor(v, 2);
    v += __shfl_xor(v, 4); v += __shfl_xor(v, 8);
    return v;
}
__device__ __forceinline__ float qred_max(float v) {
    v = fmaxf(v, __shfl_xor(v, 1)); v = fmaxf(v, __shfl_xor(v, 2));
    v = fmaxf(v, __shfl_xor(v, 4)); v = fmaxf(v, __shfl_xor(v, 8));
    return v;
}
__device__ __forceinline__ float wred_add(float x) {
#pragma unroll
    for (int off = 32; off > 0; off >>= 1) x += __shfl_xor(x, off, 64);
    return x;
}
__device__ __forceinline__ float wred_max(float x) {
#pragma unroll
    for (int off = 32; off > 0; off >>= 1) x = fmaxf(x, __shfl_xor(x, off, 64));
    return x;
}

// ---- prep: pack W, Uo (fp32 row-major [k][n]) into B-fragment-linear bf16.
// frag_id = (k/32)*16 + n/16; lane = ((k%32)/8)*16 + n%16; elem j = k%8.
// flat bf16 index e = frag_id*512 + lane*8 + j  -> one coalesced dwordx4 per wave-frag.
__global__ __launch_bounds__(256) void k_prep(
    const float* __restrict__ W, const float* __restrict__ Uo,
    __bf16* __restrict__ Wf, __bf16* __restrict__ Uf)
{
    const int e = blockIdx.x * 256 + threadIdx.x;   // 0..65535
    const int frag = e >> 9, rem = e & 511;
    const int lane = rem >> 3, j = rem & 7;
    const int kk = frag >> 4, tn = frag & 15;
    const int k = kk * 32 + (lane >> 4) * 8 + j;
    const int n = tn * 16 + (lane & 15);
    Wf[e] = (__bf16)W[k * 256 + n];
    Uf[e] = (__bf16)Uo[k * 256 + n];
}

// ---- main fused kernel: 64 rows/block, 4 waves; wave w owns cols [64w, 64w+64).
__global__ __launch_bounds__(256) void k_rows(
    const float* __restrict__ x, const float* __restrict__ mask,
    const __bf16* __restrict__ Wf, const float* __restrict__ bo,
    const float* __restrict__ u, const __bf16* __restrict__ Uf,
    float* __restrict__ vu_out, float* __restrict__ betas)
{
    __shared__ __bf16 xs[64 * XP];      // x tile, later reused for v
    __shared__ float red[4][64];        // cross-wave row reductions
    const int tid = threadIdx.x, lane = tid & 63, w = tid >> 6;
    const int quad = lane >> 4, c = lane & 15;
    const int row0 = blockIdx.x * 64;
    const bf16x8* Wf8 = (const bf16x8*)Wf;
    const bf16x8* Uf8 = (const bf16x8*)Uf;

    // stage x[64][256] fp32 -> bf16 LDS (coalesced float4 reads, b64 LDS writes)
    {
        const float4* xg = (const float4*)(x + (size_t)row0 * D_);
#pragma unroll
        for (int i = 0; i < 16; ++i) {
            const int f4 = i * 256 + tid;
            const float4 t = xg[f4];
            const int r = f4 >> 6, cc = (f4 & 63) << 2;
            bf16x4 h; h[0] = (__bf16)t.x; h[1] = (__bf16)t.y; h[2] = (__bf16)t.z; h[3] = (__bf16)t.w;
            *(bf16x4*)(xs + r * XP + cc) = h;
        }
    }
    __syncthreads();

    // ---- GEMM1: t = x @ W   (wave: 4 M-tiles x 4 N-tiles of 16x16, K=256)
    f32x4 acc[4][4];
#pragma unroll
    for (int i = 0; i < 4; ++i)
#pragma unroll
        for (int j = 0; j < 4; ++j) acc[i][j] = (f32x4){0.f, 0.f, 0.f, 0.f};

#pragma unroll
    for (int kk = 0; kk < 8; ++kk) {
        bf16x8 a[4], b[4];
#pragma unroll
        for (int i = 0; i < 4; ++i)
            a[i] = *(const bf16x8*)(xs + (i * 16 + c) * XP + kk * 32 + quad * 8);
#pragma unroll
        for (int j = 0; j < 4; ++j)
            b[j] = Wf8[(kk * 16 + w * 4 + j) * 64 + lane];
#pragma unroll
        for (int i = 0; i < 4; ++i)
#pragma unroll
            for (int j = 0; j < 4; ++j)
                acc[i][j] = __builtin_amdgcn_mfma_f32_16x16x32_bf16(a[i], b[j], acc[i][j], 0, 0, 0);
    }

    // bias + per-row sum-of-squares partials (C layout: col=c within tile, row=quad*4+reg)
    float ss[4][4];   // [i][reg]
#pragma unroll
    for (int j = 0; j < 4; ++j) {
        const float bj = bo[w * 64 + j * 16 + c];
#pragma unroll
        for (int i = 0; i < 4; ++i)
#pragma unroll
            for (int r = 0; r < 4; ++r) acc[i][j][r] += bj;
    }
#pragma unroll
    for (int i = 0; i < 4; ++i)
#pragma unroll
        for (int r = 0; r < 4; ++r) {
            float s = 0.f;
#pragma unroll
            for (int j = 0; j < 4; ++j) s += acc[i][j][r] * acc[i][j][r];
            ss[i][r] = s;
        }
    {   // wave-local 16-lane reduce; lane c==i*4+r keeps row (i*16+quad*4+r)'s partial
        float myv = 0.f;
#pragma unroll
        for (int i = 0; i < 4; ++i)
#pragma unroll
            for (int r = 0; r < 4; ++r) {
                const float p = qred_add(ss[i][r]);
                if (c == i * 4 + r) myv = p;
            }
        red[w][(c >> 2) * 16 + quad * 4 + (c & 3)] = myv;
    }
    __syncthreads();                                   // (a) K1 + R1 writes done

    float inv[4][4];
#pragma unroll
    for (int i = 0; i < 4; ++i)
#pragma unroll
        for (int r = 0; r < 4; ++r) {
            const int row = i * 16 + quad * 4 + r;
            const float t = red[0][row] + red[1][row] + red[2][row] + red[3][row];
            inv[i][r] = 1.f / fmaxf(sqrtf(t), 1e-12f);
        }

    // v = tanh(t/||t||): accumulate vu partials, write v (bf16) into xs (reuse)
    float uj[4];
#pragma unroll
    for (int j = 0; j < 4; ++j) uj[j] = u[w * 64 + j * 16 + c];
    float vup[4][4];
#pragma unroll
    for (int i = 0; i < 4; ++i)
#pragma unroll
        for (int r = 0; r < 4; ++r) vup[i][r] = 0.f;
#pragma unroll
    for (int i = 0; i < 4; ++i)
#pragma unroll
        for (int j = 0; j < 4; ++j)
#pragma unroll
            for (int r = 0; r < 4; ++r) {
                const float tv = acc[i][j][r] * inv[i][r];
                const float e2 = __expf(2.f * tv);
                const float v  = (e2 - 1.f) * __frcp_rn(e2 + 1.f);
                vup[i][r] += v * uj[j];
                xs[(i * 16 + quad * 4 + r) * XP + (w * 64 + j * 16 + c)] = (__bf16)v;
            }
    __syncthreads();                                   // (b) R1 reads + v writes done

    {
        float myv = 0.f;
#pragma unroll
        for (int i = 0; i < 4; ++i)
#pragma unroll
            for (int r = 0; r < 4; ++r) {
                const float p = qred_add(vup[i][r]);
                if (c == i * 4 + r) myv = p;
            }
        red[w][(c >> 2) * 16 + quad * 4 + (c & 3)] = myv;
    }
    __syncthreads();                                   // (c) R2 writes done

    if (tid < 64) {
        const float vu = red[0][tid] + red[1][tid] + red[2][tid] + red[3][tid];
        vu_out[row0 + tid] = vu * mask[row0 + tid];
    }

    // ---- GEMM2: vuo = v @ Uo
    f32x4 vo[4][4];
#pragma unroll
    for (int i = 0; i < 4; ++i)
#pragma unroll
        for (int j = 0; j < 4; ++j) vo[i][j] = (f32x4){0.f, 0.f, 0.f, 0.f};
#pragma unroll
    for (int kk = 0; kk < 8; ++kk) {
        bf16x8 a[4], b[4];
#pragma unroll
        for (int i = 0; i < 4; ++i)
            a[i] = *(const bf16x8*)(xs + (i * 16 + c) * XP + kk * 32 + quad * 8);
#pragma unroll
        for (int j = 0; j < 4; ++j)
            b[j] = Uf8[(kk * 16 + w * 4 + j) * 64 + lane];
#pragma unroll
        for (int i = 0; i < 4; ++i)
#pragma unroll
            for (int j = 0; j < 4; ++j)
                vo[i][j] = __builtin_amdgcn_mfma_f32_16x16x32_bf16(a[i], b[j], vo[i][j], 0, 0, 0);
    }

    // betas: masked softmax over the 256 cols of each row
    float mk[4][4];
#pragma unroll
    for (int i = 0; i < 4; ++i)
#pragma unroll
        for (int r = 0; r < 4; ++r) mk[i][r] = mask[row0 + i * 16 + quad * 4 + r];
#pragma unroll
    for (int i = 0; i < 4; ++i)
#pragma unroll
        for (int j = 0; j < 4; ++j)
#pragma unroll
            for (int r = 0; r < 4; ++r) vo[i][j][r] *= mk[i][r];

    float pm[4][4];
#pragma unroll
    for (int i = 0; i < 4; ++i)
#pragma unroll
        for (int r = 0; r < 4; ++r) {
            float m0 = vo[i][0][r];
#pragma unroll
            for (int j = 1; j < 4; ++j) m0 = fmaxf(m0, vo[i][j][r]);
            pm[i][r] = m0;
        }
    __syncthreads();                                   // (d) R2 reads done, red free
    {
        float myv = 0.f;
#pragma unroll
        for (int i = 0; i < 4; ++i)
#pragma unroll
            for (int r = 0; r < 4; ++r) {
                const float p = qred_max(pm[i][r]);
                if (c == i * 4 + r) myv = p;
            }
        red[w][(c >> 2) * 16 + quad * 4 + (c & 3)] = myv;
    }
    __syncthreads();                                   // (e) R3 writes done
    float mx[4][4];
#pragma unroll
    for (int i = 0; i < 4; ++i)
#pragma unroll
        for (int r = 0; r < 4; ++r) {
            const int row = i * 16 + quad * 4 + r;
            mx[i][r] = fmaxf(fmaxf(red[0][row], red[1][row]), fmaxf(red[2][row], red[3][row]));
        }
#pragma unroll
    for (int i = 0; i < 4; ++i)
#pragma unroll
        for (int j = 0; j < 4; ++j)
#pragma unroll
            for (int r = 0; r < 4; ++r)
                vo[i][j][r] = __expf(vo[i][j][r] - mx[i][r]) * mk[i][r];
    float psum[4][4];
#pragma unroll
    for (int i = 0; i < 4; ++i)
#pragma unroll
        for (int r = 0; r < 4; ++r) {
            float s = 0.f;
#pragma unroll
            for (int j = 0; j < 4; ++j) s += vo[i][j][r];
            psum[i][r] = s;
        }
    __syncthreads();                                   // (f) R3 reads done
    {
        float myv = 0.f;
#pragma unroll
        for (int i = 0; i < 4; ++i)
#pragma unroll
            for (int r = 0; r < 4; ++r) {
                const float p = qred_add(psum[i][r]);
                if (c == i * 4 + r) myv = p;
            }
        red[w][(c >> 2) * 16 + quad * 4 + (c & 3)] = myv;
    }
    __syncthreads();                                   // (g) R4 writes done
#pragma unroll
    for (int i = 0; i < 4; ++i)
#pragma unroll
        for (int r = 0; r < 4; ++r) {
            const int row = i * 16 + quad * 4 + r;
            const float s = red[0][row] + red[1][row] + red[2][row] + red[3][row];
            const float rs = 1.f / ((s == 0.f) ? 1.f : s);
            float* dst = betas + (size_t)(row0 + row) * D_ + w * 64 + c;
#pragma unroll
            for (int j = 0; j < 4; ++j) dst[j * 16] = vo[i][j][r] * rs;
        }
}

// One block per batch b: masked softmax over S (in-place on the vu/alphas region).
__global__ __launch_bounds__(256) void k_alphas(
    const float* __restrict__ mask, float* __restrict__ a)
{
    const int b = blockIdx.x;
    const int tid = threadIdx.x, lane = tid & 63, wid = tid >> 6;
    __shared__ float red[4];
    const int base = b * S_;
    float vals[4], mkv[4];
#pragma unroll
    for (int k = 0; k < 4; ++k) {
        vals[k] = a[base + tid + 256 * k];
        mkv[k]  = mask[base + tid + 256 * k];
    }
    float mx = fmaxf(fmaxf(vals[0], vals[1]), fmaxf(vals[2], vals[3]));
    mx = wred_max(mx);
    if (lane == 0) red[wid] = mx;
    __syncthreads();
    mx = fmaxf(fmaxf(red[0], red[1]), fmaxf(red[2], red[3]));
    __syncthreads();
    float e[4], s = 0.f;
#pragma unroll
    for (int k = 0; k < 4; ++k) { e[k] = expf(vals[k] - mx) * mkv[k]; s += e[k]; }
    s = wred_add(s);
    if (lane == 0) red[wid] = s;
    __syncthreads();
    s = red[0] + red[1] + red[2] + red[3];
    const float r = 1.f / ((s == 0.f) ? 1.f : s);
#pragma unroll
    for (int k = 0; k < 4; ++k) a[base + tid + 256 * k] = e[k] * r;
}

// out[b,d] = sum_s alphas * betas * x; 32 chunks per batch for occupancy.
__global__ __launch_bounds__(256) void k_out(
    const float* __restrict__ x, const float* __restrict__ alphas,
    const float* __restrict__ betas, float* __restrict__ out)
{
    const int bx = blockIdx.x;
    const int b = bx >> 5, chunk = bx & 31;
    const int tid = threadIdx.x;
    float acc = 0.f;
    const int sbeg = chunk * 32;
    for (int si = 0; si < 32; ++si) {
        const int s = sbeg + si;
        const float al = alphas[b * S_ + s];
        if (al != 0.f) {
            const size_t off = (size_t)(b * S_ + s) * D_ + tid;
            acc += al * betas[off] * x[off];
        }
    }
    atomicAdd(&out[b * D_ + tid], acc);
}

extern "C" void kernel_launch(void* const* d_in, const int* in_sizes, int n_in,
                              void* d_out, int out_size, void* d_ws, size_t ws_size,
                              hipStream_t stream) {
    const float* x    = (const float*)d_in[0];
    const float* mask = (const float*)d_in[1];
    const float* W    = (const float*)d_in[2];
    const float* bo   = (const float*)d_in[3];
    const float* u    = (const float*)d_in[4];
    const float* Uo   = (const float*)d_in[5];

    float* out    = (float*)d_out;             // [B, 256]
    float* alphas = out + B_ * D_;             // [B, S]
    float* betas  = alphas + (size_t)B_ * S_;  // [B, S, 256]

    __bf16* Wf = (__bf16*)d_ws;                // 65536 bf16 = 128 KB
    __bf16* Uf = Wf + 65536;                   // 128 KB (ws_size must be >= 256 KB)

    hipMemsetAsync(out, 0, (size_t)B_ * D_ * sizeof(float), stream);
    k_prep  <<<256,          256, 0, stream>>>(W, Uo, Wf, Uf);
    k_rows  <<<B_ * S_ / 64, 256, 0, stream>>>(x, mask, Wf, bo, u, Uf, alphas, betas);
    k_alphas<<<B_,           256, 0, stream>>>(mask, alphas);
    k_out   <<<B_ * 32,      256, 0, stream>>>(x, alphas, betas, out);
}

// Round 3
// 334.412 us; speedup vs baseline: 2.3955x; 1.1433x over previous
//
#include <hip/hip_runtime.h>
#include <math.h>

#define B_ 128
#define S_ 1024
#define D_ 256          // D == A == O == 256
#define XP 264          // LDS bf16 row pitch (132 dwords ≡ 4 mod 32 banks)
#define ROWS 32         // rows per block

using bf16x8 = __attribute__((ext_vector_type(8))) __bf16;
using bf16x4 = __attribute__((ext_vector_type(4))) __bf16;
using f32x4  = __attribute__((ext_vector_type(4))) float;

__device__ __forceinline__ float qred_add(float v) {   // reduce across 16-lane group
    v += __shfl_xor(v, 1); v += __shfl_xor(v, 2);
    v += __shfl_xor(v, 4); v += __shfl_xor(v, 8);
    return v;
}
__device__ __forceinline__ float qred_max(float v) {
    v = fmaxf(v, __shfl_xor(v, 1)); v = fmaxf(v, __shfl_xor(v, 2));
    v = fmaxf(v, __shfl_xor(v, 4)); v = fmaxf(v, __shfl_xor(v, 8));
    return v;
}
__device__ __forceinline__ float wred_add(float x) {
#pragma unroll
    for (int off = 32; off > 0; off >>= 1) x += __shfl_xor(x, off, 64);
    return x;
}

// ---- prep: pack W, Uo (fp32 row-major [k][n]) into B-fragment-linear bf16.
__global__ __launch_bounds__(256) void k_prep(
    const float* __restrict__ W, const float* __restrict__ Uo,
    __bf16* __restrict__ Wf, __bf16* __restrict__ Uf)
{
    const int e = blockIdx.x * 256 + threadIdx.x;   // 0..65535
    const int frag = e >> 9, rem = e & 511;
    const int lane = rem >> 3, j = rem & 7;
    const int kk = frag >> 4, tn = frag & 15;
    const int k = kk * 32 + (lane >> 4) * 8 + j;
    const int n = tn * 16 + (lane & 15);
    Wf[e] = (__bf16)W[k * 256 + n];
    Uf[e] = (__bf16)Uo[k * 256 + n];
}

// ---- main fused kernel: 32 rows/block, 4 waves; wave w owns cols [64w, 64w+64).
__global__ __launch_bounds__(256, 4) void k_rows(
    const float* __restrict__ x, const float* __restrict__ mask,
    const __bf16* __restrict__ Wf, const float* __restrict__ bo,
    const float* __restrict__ u, const __bf16* __restrict__ Uf,
    float* __restrict__ e_out,    // [B*S] unnormalized exp(vu)*mask (alphas region)
    float* __restrict__ betas,    // [B*S, 256]
    float* __restrict__ part,     // [gridDim.x, 256] per-block out partials (ws)
    float* __restrict__ outraw,   // [B,256] atomic fallback accumulator
    const int use_part)
{
    __shared__ __bf16 xs[ROWS * XP];    // x tile (bf16), later reused for v
    __shared__ float red[4][ROWS];      // cross-wave row reductions
    const int tid = threadIdx.x, lane = tid & 63, w = tid >> 6;
    const int quad = lane >> 4, c = lane & 15;
    const int row0 = blockIdx.x * ROWS;
    const bf16x8* Wf8 = (const bf16x8*)Wf;
    const bf16x8* Uf8 = (const bf16x8*)Uf;

    // stage x[32][256] fp32 -> bf16 LDS (each wave writes one full row per iter)
    {
        const float4* xg = (const float4*)(x + (size_t)row0 * D_);
#pragma unroll
        for (int it = 0; it < 8; ++it) {
            const int r = it * 4 + w;
            const float4 t = xg[r * 64 + lane];
            bf16x4 h; h[0] = (__bf16)t.x; h[1] = (__bf16)t.y; h[2] = (__bf16)t.z; h[3] = (__bf16)t.w;
            *(bf16x4*)(xs + r * XP + lane * 4) = h;
        }
    }

    // per-row mask (row = i*16 + quad*4 + r)
    float mk[2][4];
#pragma unroll
    for (int i = 0; i < 2; ++i)
#pragma unroll
        for (int r = 0; r < 4; ++r) mk[i][r] = mask[row0 + i * 16 + quad * 4 + r];

    __syncthreads();

    // ---- GEMM1: t = x @ W   (wave: 2 M-tiles x 4 N-tiles of 16x16, K=256)
    f32x4 acc[2][4];
#pragma unroll
    for (int i = 0; i < 2; ++i)
#pragma unroll
        for (int j = 0; j < 4; ++j) acc[i][j] = (f32x4){0.f, 0.f, 0.f, 0.f};
#pragma unroll
    for (int kk = 0; kk < 8; ++kk) {
        bf16x8 a[2], b[4];
#pragma unroll
        for (int i = 0; i < 2; ++i)
            a[i] = *(const bf16x8*)(xs + (i * 16 + c) * XP + kk * 32 + quad * 8);
#pragma unroll
        for (int j = 0; j < 4; ++j)
            b[j] = Wf8[(kk * 16 + w * 4 + j) * 64 + lane];
#pragma unroll
        for (int i = 0; i < 2; ++i)
#pragma unroll
            for (int j = 0; j < 4; ++j)
                acc[i][j] = __builtin_amdgcn_mfma_f32_16x16x32_bf16(a[i], b[j], acc[i][j], 0, 0, 0);
    }

    // bias + row sum-of-squares partials (C layout: col=c, row=quad*4+reg within tile)
#pragma unroll
    for (int j = 0; j < 4; ++j) {
        const float bj = bo[w * 64 + j * 16 + c];
#pragma unroll
        for (int i = 0; i < 2; ++i)
#pragma unroll
            for (int r = 0; r < 4; ++r) acc[i][j][r] += bj;
    }
    {
        float myv = 0.f;
#pragma unroll
        for (int i = 0; i < 2; ++i)
#pragma unroll
            for (int r = 0; r < 4; ++r) {
                float s = 0.f;
#pragma unroll
                for (int j = 0; j < 4; ++j) s += acc[i][j][r] * acc[i][j][r];
                const float p = qred_add(s);
                if (c == i * 4 + r) myv = p;   // c<8 lanes keep a row partial
            }
        if (c < 8) red[w][(c >> 2) * 16 + quad * 4 + (c & 3)] = myv;
    }
    __syncthreads();                                   // (a)

    float inv[2][4];
#pragma unroll
    for (int i = 0; i < 2; ++i)
#pragma unroll
        for (int r = 0; r < 4; ++r) {
            const int row = i * 16 + quad * 4 + r;
            const float t = red[0][row] + red[1][row] + red[2][row] + red[3][row];
            inv[i][r] = 1.f / fmaxf(sqrtf(t), 1e-12f);
        }

    // v = tanh(t/||t||): vu partials, write v (bf16) into xs (reuse)
    float uj[4];
#pragma unroll
    for (int j = 0; j < 4; ++j) uj[j] = u[w * 64 + j * 16 + c];
    float vup[2][4];
#pragma unroll
    for (int i = 0; i < 2; ++i)
#pragma unroll
        for (int r = 0; r < 4; ++r) vup[i][r] = 0.f;
#pragma unroll
    for (int i = 0; i < 2; ++i)
#pragma unroll
        for (int j = 0; j < 4; ++j)
#pragma unroll
            for (int r = 0; r < 4; ++r) {
                const float tv = acc[i][j][r] * inv[i][r];
                const float e2 = __expf(2.f * tv);
                const float v  = (e2 - 1.f) * __frcp_rn(e2 + 1.f);
                vup[i][r] += v * uj[j];
                xs[(i * 16 + quad * 4 + r) * XP + (w * 64 + j * 16 + c)] = (__bf16)v;
            }
    __syncthreads();                                   // (b) R1 reads + v writes done
    {
        float myv = 0.f;
#pragma unroll
        for (int i = 0; i < 2; ++i)
#pragma unroll
            for (int r = 0; r < 4; ++r) {
                const float p = qred_add(vup[i][r]);
                if (c == i * 4 + r) myv = p;
            }
        if (c < 8) red[w][(c >> 2) * 16 + quad * 4 + (c & 3)] = myv;
    }
    __syncthreads();                                   // (c)

    // e = exp(vu)*mask per row (max-shift cancels in softmax; |vu| <= ~10)
    float ee[2][4];
#pragma unroll
    for (int i = 0; i < 2; ++i)
#pragma unroll
        for (int r = 0; r < 4; ++r) {
            const int row = i * 16 + quad * 4 + r;
            const float vu = red[0][row] + red[1][row] + red[2][row] + red[3][row];
            ee[i][r] = __expf(vu) * mk[i][r];
        }
    if (tid < ROWS) {
        const float vu = red[0][tid] + red[1][tid] + red[2][tid] + red[3][tid];
        e_out[row0 + tid] = __expf(vu) * mask[row0 + tid];
    }

    // ---- GEMM2: vuo = v @ Uo
    f32x4 vo[2][4];
#pragma unroll
    for (int i = 0; i < 2; ++i)
#pragma unroll
        for (int j = 0; j < 4; ++j) vo[i][j] = (f32x4){0.f, 0.f, 0.f, 0.f};
#pragma unroll
    for (int kk = 0; kk < 8; ++kk) {
        bf16x8 a[2], b[4];
#pragma unroll
        for (int i = 0; i < 2; ++i)
            a[i] = *(const bf16x8*)(xs + (i * 16 + c) * XP + kk * 32 + quad * 8);
#pragma unroll
        for (int j = 0; j < 4; ++j)
            b[j] = Uf8[(kk * 16 + w * 4 + j) * 64 + lane];
#pragma unroll
        for (int i = 0; i < 2; ++i)
#pragma unroll
            for (int j = 0; j < 4; ++j)
                vo[i][j] = __builtin_amdgcn_mfma_f32_16x16x32_bf16(a[i], b[j], vo[i][j], 0, 0, 0);
    }

    // betas: masked softmax over 256 cols of each row
#pragma unroll
    for (int i = 0; i < 2; ++i)
#pragma unroll
        for (int j = 0; j < 4; ++j)
#pragma unroll
            for (int r = 0; r < 4; ++r) vo[i][j][r] *= mk[i][r];
    __syncthreads();                                   // (d) red free
    {
        float myv = 0.f;
#pragma unroll
        for (int i = 0; i < 2; ++i)
#pragma unroll
            for (int r = 0; r < 4; ++r) {
                float m0 = vo[i][0][r];
#pragma unroll
                for (int j = 1; j < 4; ++j) m0 = fmaxf(m0, vo[i][j][r]);
                const float p = qred_max(m0);
                if (c == i * 4 + r) myv = p;
            }
        if (c < 8) red[w][(c >> 2) * 16 + quad * 4 + (c & 3)] = myv;
    }
    __syncthreads();                                   // (e)
#pragma unroll
    for (int i = 0; i < 2; ++i)
#pragma unroll
        for (int r = 0; r < 4; ++r) {
            const int row = i * 16 + quad * 4 + r;
            const float mx = fmaxf(fmaxf(red[0][row], red[1][row]), fmaxf(red[2][row], red[3][row]));
#pragma unroll
            for (int j = 0; j < 4; ++j)
                vo[i][j][r] = __expf(vo[i][j][r] - mx) * mk[i][r];
        }
    __syncthreads();                                   // (f)
    {
        float myv = 0.f;
#pragma unroll
        for (int i = 0; i < 2; ++i)
#pragma unroll
            for (int r = 0; r < 4; ++r) {
                float s = 0.f;
#pragma unroll
                for (int j = 0; j < 4; ++j) s += vo[i][j][r];
                const float p = qred_add(s);
                if (c == i * 4 + r) myv = p;
            }
        if (c < 8) red[w][(c >> 2) * 16 + quad * 4 + (c & 3)] = myv;
    }
    __syncthreads();                                   // (g)
    float rs[2][4];
#pragma unroll
    for (int i = 0; i < 2; ++i)
#pragma unroll
        for (int r = 0; r < 4; ++r) {
            const int row = i * 16 + quad * 4 + r;
            const float s = red[0][row] + red[1][row] + red[2][row] + red[3][row];
            rs[i][r] = 1.f / ((s == 0.f) ? 1.f : s);
            float* dst = betas + (size_t)(row0 + row) * D_ + w * 64 + c;
#pragma unroll
            for (int j = 0; j < 4; ++j) dst[j * 16] = vo[i][j][r] * rs[i][r];
        }

    // ---- fused out-partials: opart[j] = sum_rows e*beta*x (x re-read fp32; skip masked)
    float opart[4] = {0.f, 0.f, 0.f, 0.f};
#pragma unroll
    for (int i = 0; i < 2; ++i)
#pragma unroll
        for (int r = 0; r < 4; ++r) {
            const float fw = ee[i][r] * rs[i][r];
            if (fw != 0.f) {
                const int row = i * 16 + quad * 4 + r;
                const float* xr = x + (size_t)(row0 + row) * D_ + w * 64 + c;
#pragma unroll
                for (int j = 0; j < 4; ++j) opart[j] += fw * vo[i][j][r] * xr[j * 16];
            }
        }
#pragma unroll
    for (int j = 0; j < 4; ++j) {   // reduce across the 4 quads (rows of block)
        opart[j] += __shfl_xor(opart[j], 16);
        opart[j] += __shfl_xor(opart[j], 32);
    }
    if (quad == 0) {
        const int b = row0 >> 10;
#pragma unroll
        for (int j = 0; j < 4; ++j) {
            const int col = w * 64 + j * 16 + c;
            if (use_part) part[(size_t)blockIdx.x * D_ + col] = opart[j];
            else atomicAdd(&outraw[b * D_ + col], opart[j]);
        }
    }
}

// ---- final: Z per batch, normalize alphas in place, reduce out partials.
__global__ __launch_bounds__(256) void k_fin(
    const float* __restrict__ part, float* __restrict__ e_alphas,
    float* __restrict__ out, const int use_part)
{
    const int b = blockIdx.x;
    const int tid = threadIdx.x, lane = tid & 63, wid = tid >> 6;
    __shared__ float red[4];
    const int base = b * S_;
    float ev[4];
#pragma unroll
    for (int k = 0; k < 4; ++k) ev[k] = e_alphas[base + tid + 256 * k];
    float s = ev[0] + ev[1] + ev[2] + ev[3];
    s = wred_add(s);
    if (lane == 0) red[wid] = s;
    __syncthreads();
    const float Z = red[0] + red[1] + red[2] + red[3];
    const float Zr = 1.f / ((Z == 0.f) ? 1.f : Z);
#pragma unroll
    for (int k = 0; k < 4; ++k) e_alphas[base + tid + 256 * k] = ev[k] * Zr;

    float acc;
    if (use_part) {
        acc = 0.f;
#pragma unroll
        for (int k = 0; k < 32; ++k) acc += part[(size_t)(b * 32 + k) * D_ + tid];
    } else {
        acc = out[b * D_ + tid];
    }
    out[b * D_ + tid] = acc * Zr;
}

extern "C" void kernel_launch(void* const* d_in, const int* in_sizes, int n_in,
                              void* d_out, int out_size, void* d_ws, size_t ws_size,
                              hipStream_t stream) {
    const float* x    = (const float*)d_in[0];
    const float* mask = (const float*)d_in[1];
    const float* W    = (const float*)d_in[2];
    const float* bo   = (const float*)d_in[3];
    const float* u    = (const float*)d_in[4];
    const float* Uo   = (const float*)d_in[5];

    float* out    = (float*)d_out;             // [B, 256]
    float* alphas = out + B_ * D_;             // [B, S]
    float* betas  = alphas + (size_t)B_ * S_;  // [B, S, 256]

    __bf16* Wf = (__bf16*)d_ws;                // 128 KB
    __bf16* Uf = Wf + 65536;                   // 128 KB
    float* part = (float*)(Uf + 65536);        // 4096*256*4 = 4 MB (if it fits)

    const int nblk = B_ * S_ / ROWS;           // 4096
    const size_t need = 2 * 65536 * sizeof(__bf16) + (size_t)nblk * D_ * sizeof(float);
    const int use_part = (ws_size >= need) ? 1 : 0;

    hipMemsetAsync(out, 0, (size_t)B_ * D_ * sizeof(float), stream);  // atomic-path init
    k_prep<<<256, 256, 0, stream>>>(W, Uo, Wf, Uf);
    k_rows<<<nblk, 256, 0, stream>>>(x, mask, Wf, bo, u, Uf, alphas, betas, part, out, use_part);
    k_fin <<<B_,   256, 0, stream>>>(part, alphas, out, use_part);
}

// Round 4
// 325.493 us; speedup vs baseline: 2.4612x; 1.0274x over previous
//
#include <hip/hip_runtime.h>
#include <math.h>

#define B_ 128
#define S_ 1024
#define D_ 256          // D == A == O == 256
#define XP 264          // LDS bf16 row pitch for x/v tile (528 B, 16B-aligned)
#define TP 68           // LDS fp32 row pitch for transpose buffer (272 B, 16B-aligned)
#define ROWS 32         // rows per block

using bf16x8 = __attribute__((ext_vector_type(8))) __bf16;
using bf16x4 = __attribute__((ext_vector_type(4))) __bf16;
using f32x4  = __attribute__((ext_vector_type(4))) float;

__device__ __forceinline__ float qred_add(float v) {   // reduce across 16-lane group
    v += __shfl_xor(v, 1); v += __shfl_xor(v, 2);
    v += __shfl_xor(v, 4); v += __shfl_xor(v, 8);
    return v;
}
__device__ __forceinline__ float wred_add(float x) {
#pragma unroll
    for (int off = 32; off > 0; off >>= 1) x += __shfl_xor(x, off, 64);
    return x;
}

// ---- prep: pack W, Uo (fp32 row-major [k][n]) into B-fragment-linear bf16.
__global__ __launch_bounds__(256) void k_prep(
    const float* __restrict__ W, const float* __restrict__ Uo,
    __bf16* __restrict__ Wf, __bf16* __restrict__ Uf)
{
    const int e = blockIdx.x * 256 + threadIdx.x;   // 0..65535
    const int frag = e >> 9, rem = e & 511;
    const int lane = rem >> 3, j = rem & 7;
    const int kk = frag >> 4, tn = frag & 15;
    const int k = kk * 32 + (lane >> 4) * 8 + j;
    const int n = tn * 16 + (lane & 15);
    Wf[e] = (__bf16)W[k * 256 + n];
    Uf[e] = (__bf16)Uo[k * 256 + n];
}

// ---- main fused kernel: 32 rows/block, 4 waves; wave w owns cols [64w, 64w+64).
__global__ __launch_bounds__(256, 4) void k_rows(
    const float* __restrict__ x, const float* __restrict__ mask,
    const __bf16* __restrict__ Wf, const float* __restrict__ bo,
    const float* __restrict__ u, const __bf16* __restrict__ Uf,
    float* __restrict__ e_out,    // [B*S] unnormalized exp(vu)*mask (alphas region)
    float* __restrict__ betas,    // [B*S, 256]
    float* __restrict__ part,     // [gridDim.x, 256] per-block out partials (ws)
    float* __restrict__ outraw,   // [B,256] atomic fallback accumulator
    const int use_part)
{
    // xs (bf16 x/v tile, 16896 B) aliased with trans (fp32 transpose buf, 17408 B)
    __shared__ __align__(16) char smem[4 * 16 * TP * 4];
    __bf16* xs   = (__bf16*)smem;
    float* trans = (float*)smem;
    __shared__ float red[4][ROWS];
    const int tid = threadIdx.x, lane = tid & 63, w = tid >> 6;
    const int quad = lane >> 4, c = lane & 15;
    const int hi = lane >> 4, c4 = lane & 15;      // store-phase decomposition
    const int row0 = blockIdx.x * ROWS;
    const bf16x8* Wf8 = (const bf16x8*)Wf;
    const bf16x8* Uf8 = (const bf16x8*)Uf;

    // stage x[32][256] fp32 -> bf16 LDS
    {
        const float4* xg = (const float4*)(x + (size_t)row0 * D_);
#pragma unroll
        for (int it = 0; it < 8; ++it) {
            const int r = it * 4 + w;
            const float4 t = xg[r * 64 + lane];
            bf16x4 h; h[0] = (__bf16)t.x; h[1] = (__bf16)t.y; h[2] = (__bf16)t.z; h[3] = (__bf16)t.w;
            *(bf16x4*)(xs + r * XP + lane * 4) = h;
        }
    }

    float mk[2][4];   // mask in (quad,r) mapping
#pragma unroll
    for (int i = 0; i < 2; ++i)
#pragma unroll
        for (int r = 0; r < 4; ++r) mk[i][r] = mask[row0 + i * 16 + quad * 4 + r];

    __syncthreads();                                   // sync0

    // ---- GEMM1: t = x @ W
    f32x4 acc[2][4];
#pragma unroll
    for (int i = 0; i < 2; ++i)
#pragma unroll
        for (int j = 0; j < 4; ++j) acc[i][j] = (f32x4){0.f, 0.f, 0.f, 0.f};
#pragma unroll
    for (int kk = 0; kk < 8; ++kk) {
        bf16x8 a[2], b[4];
#pragma unroll
        for (int i = 0; i < 2; ++i)
            a[i] = *(const bf16x8*)(xs + (i * 16 + c) * XP + kk * 32 + quad * 8);
#pragma unroll
        for (int j = 0; j < 4; ++j)
            b[j] = Wf8[(kk * 16 + w * 4 + j) * 64 + lane];
#pragma unroll
        for (int i = 0; i < 2; ++i)
#pragma unroll
            for (int j = 0; j < 4; ++j)
                acc[i][j] = __builtin_amdgcn_mfma_f32_16x16x32_bf16(a[i], b[j], acc[i][j], 0, 0, 0);
    }

    // bias + row sum-of-squares partials
#pragma unroll
    for (int j = 0; j < 4; ++j) {
        const float bj = bo[w * 64 + j * 16 + c];
#pragma unroll
        for (int i = 0; i < 2; ++i)
#pragma unroll
            for (int r = 0; r < 4; ++r) acc[i][j][r] += bj;
    }
    {
        float myv = 0.f;
#pragma unroll
        for (int i = 0; i < 2; ++i)
#pragma unroll
            for (int r = 0; r < 4; ++r) {
                float s = 0.f;
#pragma unroll
                for (int j = 0; j < 4; ++j) s += acc[i][j][r] * acc[i][j][r];
                const float p = qred_add(s);
                if (c == i * 4 + r) myv = p;
            }
        if (c < 8) red[w][(c >> 2) * 16 + quad * 4 + (c & 3)] = myv;
    }
    __syncthreads();                                   // (a)

    float inv[2][4];
#pragma unroll
    for (int i = 0; i < 2; ++i)
#pragma unroll
        for (int r = 0; r < 4; ++r) {
            const int row = i * 16 + quad * 4 + r;
            const float t = red[0][row] + red[1][row] + red[2][row] + red[3][row];
            inv[i][r] = 1.f / fmaxf(sqrtf(t), 1e-12f);
        }

    // v = tanh(t/||t||): vu partials, write v (bf16) into xs (reuse)
    float uj[4];
#pragma unroll
    for (int j = 0; j < 4; ++j) uj[j] = u[w * 64 + j * 16 + c];
    float vup[2][4];
#pragma unroll
    for (int i = 0; i < 2; ++i)
#pragma unroll
        for (int r = 0; r < 4; ++r) vup[i][r] = 0.f;
#pragma unroll
    for (int i = 0; i < 2; ++i)
#pragma unroll
        for (int j = 0; j < 4; ++j)
#pragma unroll
            for (int r = 0; r < 4; ++r) {
                const float tv = acc[i][j][r] * inv[i][r];
                const float e2 = __expf(2.f * tv);
                const float v  = (e2 - 1.f) * __frcp_rn(e2 + 1.f);
                vup[i][r] += v * uj[j];
                xs[(i * 16 + quad * 4 + r) * XP + (w * 64 + j * 16 + c)] = (__bf16)v;
            }
    __syncthreads();                                   // (b) R1 reads + v writes done
    {
        float myv = 0.f;
#pragma unroll
        for (int i = 0; i < 2; ++i)
#pragma unroll
            for (int r = 0; r < 4; ++r) {
                const float p = qred_add(vup[i][r]);
                if (c == i * 4 + r) myv = p;
            }
        if (c < 8) red[w][(c >> 2) * 16 + quad * 4 + (c & 3)] = myv;
    }
    __syncthreads();                                   // (c) vu available in red

    // ev in store mapping: row r_ip = i*16 + hi + p*4
    float ev[2][4];
#pragma unroll
    for (int i = 0; i < 2; ++i)
#pragma unroll
        for (int p = 0; p < 4; ++p) {
            const int rr = i * 16 + hi + p * 4;
            const float vu = red[0][rr] + red[1][rr] + red[2][rr] + red[3][rr];
            ev[i][p] = __expf(vu) * mask[row0 + rr];
        }
    if (tid < ROWS) {
        const float vu = red[0][tid] + red[1][tid] + red[2][tid] + red[3][tid];
        e_out[row0 + tid] = __expf(vu) * mask[row0 + tid];
    }

    // ---- GEMM2: vuo = v @ Uo
    f32x4 vo[2][4];
#pragma unroll
    for (int i = 0; i < 2; ++i)
#pragma unroll
        for (int j = 0; j < 4; ++j) vo[i][j] = (f32x4){0.f, 0.f, 0.f, 0.f};
#pragma unroll
    for (int kk = 0; kk < 8; ++kk) {
        bf16x8 a[2], b[4];
#pragma unroll
        for (int i = 0; i < 2; ++i)
            a[i] = *(const bf16x8*)(xs + (i * 16 + c) * XP + kk * 32 + quad * 8);
#pragma unroll
        for (int j = 0; j < 4; ++j)
            b[j] = Uf8[(kk * 16 + w * 4 + j) * 64 + lane];
#pragma unroll
        for (int i = 0; i < 2; ++i)
#pragma unroll
            for (int j = 0; j < 4; ++j)
                vo[i][j] = __builtin_amdgcn_mfma_f32_16x16x32_bf16(a[i], b[j], vo[i][j], 0, 0, 0);
    }

    // betas numerator: exp(vuo*mask)*mask  (no max shift: |vuo| <= ~10, cancels exactly)
#pragma unroll
    for (int i = 0; i < 2; ++i)
#pragma unroll
        for (int j = 0; j < 4; ++j)
#pragma unroll
            for (int r = 0; r < 4; ++r) {
                const float t = vo[i][j][r] * mk[i][r];
                vo[i][j][r] = __expf(t) * mk[i][r];
            }
    // row sums
    float psum[2][4];
#pragma unroll
    for (int i = 0; i < 2; ++i)
#pragma unroll
        for (int r = 0; r < 4; ++r) {
            float s = 0.f;
#pragma unroll
            for (int j = 0; j < 4; ++j) s += vo[i][j][r];
            psum[i][r] = s;
        }
    __syncthreads();                                   // (d') ev/red reads + GEMM2 xs reads done
    {
        float myv = 0.f;
#pragma unroll
        for (int i = 0; i < 2; ++i)
#pragma unroll
            for (int r = 0; r < 4; ++r) {
                const float p = qred_add(psum[i][r]);
                if (c == i * 4 + r) myv = p;
            }
        if (c < 8) red[w][(c >> 2) * 16 + quad * 4 + (c & 3)] = myv;
    }
    __syncthreads();                                   // (e') beta sums in red

    // rs in store mapping
    float rs[2][4];
#pragma unroll
    for (int i = 0; i < 2; ++i)
#pragma unroll
        for (int p = 0; p < 4; ++p) {
            const int rr = i * 16 + hi + p * 4;
            const float s = red[0][rr] + red[1][rr] + red[2][rr] + red[3][rr];
            rs[i][p] = 1.f / ((s == 0.f) ? 1.f : s);
        }

    // ---- epilogue: LDS transpose (wave-private slice) -> coalesced float4 stores,
    //      fused out-partials with coalesced masked x re-read.
    float* tw = trans + w * (16 * TP);
    f32x4 opart = (f32x4){0.f, 0.f, 0.f, 0.f};
#pragma unroll
    for (int i = 0; i < 2; ++i) {
        asm volatile("s_waitcnt lgkmcnt(0)" ::: "memory");  // prior trans reads drained (WAR)
#pragma unroll
        for (int j = 0; j < 4; ++j)
#pragma unroll
            for (int r = 0; r < 4; ++r)
                tw[(quad * 4 + r) * TP + j * 16 + c] = vo[i][j][r];
        asm volatile("s_waitcnt lgkmcnt(0)" ::: "memory");  // writes visible (RAW)
#pragma unroll
        for (int p = 0; p < 4; ++p) {
            const int rl = hi + p * 4;                      // local row 0..15
            f32x4 b4 = *(const f32x4*)&tw[rl * TP + c4 * 4];
            const float rsv = rs[i][p];
            b4[0] *= rsv; b4[1] *= rsv; b4[2] *= rsv; b4[3] *= rsv;
            const size_t goff = (size_t)(row0 + i * 16 + rl) * D_ + w * 64 + c4 * 4;
            *(f32x4*)&betas[goff] = b4;                     // 256-B contiguous per 16 lanes
            const float evv = ev[i][p];
            if (evv != 0.f) {                               // 16-lane-uniform skip
                const f32x4 x4 = *(const f32x4*)&x[goff];
                opart[0] += evv * b4[0] * x4[0];
                opart[1] += evv * b4[1] * x4[1];
                opart[2] += evv * b4[2] * x4[2];
                opart[3] += evv * b4[3] * x4[3];
            }
        }
    }
    // reduce across the 4 row-groups
#pragma unroll
    for (int k = 0; k < 4; ++k) {
        opart[k] += __shfl_xor(opart[k], 16);
        opart[k] += __shfl_xor(opart[k], 32);
    }
    if (lane < 16) {
        const int col = w * 64 + c4 * 4;
        if (use_part) {
            *(f32x4*)&part[(size_t)blockIdx.x * D_ + col] = opart;
        } else {
            const int b = row0 >> 10;
#pragma unroll
            for (int k = 0; k < 4; ++k) atomicAdd(&outraw[b * D_ + col + k], opart[k]);
        }
    }
}

// ---- final: Z per batch, normalize alphas in place, reduce out partials.
__global__ __launch_bounds__(256) void k_fin(
    const float* __restrict__ part, float* __restrict__ e_alphas,
    float* __restrict__ out, const int use_part)
{
    const int b = blockIdx.x;
    const int tid = threadIdx.x, lane = tid & 63, wid = tid >> 6;
    __shared__ float red[4];
    const int base = b * S_;
    float ev[4];
#pragma unroll
    for (int k = 0; k < 4; ++k) ev[k] = e_alphas[base + tid + 256 * k];
    float s = ev[0] + ev[1] + ev[2] + ev[3];
    s = wred_add(s);
    if (lane == 0) red[wid] = s;
    __syncthreads();
    const float Z = red[0] + red[1] + red[2] + red[3];
    const float Zr = 1.f / ((Z == 0.f) ? 1.f : Z);
#pragma unroll
    for (int k = 0; k < 4; ++k) e_alphas[base + tid + 256 * k] = ev[k] * Zr;

    float acc;
    if (use_part) {
        acc = 0.f;
#pragma unroll
        for (int k = 0; k < 32; ++k) acc += part[(size_t)(b * 32 + k) * D_ + tid];
    } else {
        acc = out[b * D_ + tid];
    }
    out[b * D_ + tid] = acc * Zr;
}

extern "C" void kernel_launch(void* const* d_in, const int* in_sizes, int n_in,
                              void* d_out, int out_size, void* d_ws, size_t ws_size,
                              hipStream_t stream) {
    const float* x    = (const float*)d_in[0];
    const float* mask = (const float*)d_in[1];
    const float* W    = (const float*)d_in[2];
    const float* bo   = (const float*)d_in[3];
    const float* u    = (const float*)d_in[4];
    const float* Uo   = (const float*)d_in[5];

    float* out    = (float*)d_out;             // [B, 256]
    float* alphas = out + B_ * D_;             // [B, S]
    float* betas  = alphas + (size_t)B_ * S_;  // [B, S, 256]

    __bf16* Wf = (__bf16*)d_ws;                // 128 KB
    __bf16* Uf = Wf + 65536;                   // 128 KB
    float* part = (float*)(Uf + 65536);        // 4096*256*4 = 4 MB (if it fits)

    const int nblk = B_ * S_ / ROWS;           // 4096
    const size_t need = 2 * 65536 * sizeof(__bf16) + (size_t)nblk * D_ * sizeof(float);
    const int use_part = (ws_size >= need) ? 1 : 0;

    if (!use_part)
        hipMemsetAsync(out, 0, (size_t)B_ * D_ * sizeof(float), stream);
    k_prep<<<256, 256, 0, stream>>>(W, Uo, Wf, Uf);
    k_rows<<<nblk, 256, 0, stream>>>(x, mask, Wf, bo, u, Uf, alphas, betas, part, out, use_part);
    k_fin <<<B_,   256, 0, stream>>>(part, alphas, out, use_part);
}